// Round 3
// baseline (431.391 us; speedup 1.0000x reference)
//
#include <hip/hip_runtime.h>
#include <cstdint>

#define N_TOK 4096
#define DMODEL 1024
#define DFFC 2048
#define NEXP 8
#define NR (N_TOK*2)      /* 8192 expanded rows (top-2) */
#define NRP (NR+256)      /* padded for BM=256 tile overrun */

typedef unsigned short ushort_t;
typedef __attribute__((ext_vector_type(8))) short short8v;   // 8 bf16
typedef __attribute__((ext_vector_type(4))) float float4v;   // MFMA C/D

__device__ __forceinline__ ushort_t f2bf(float f){
  union { float f; unsigned u; } v; v.f = f;
  unsigned r = v.u + 0x7fffu + ((v.u >> 16) & 1u);
  return (ushort_t)(r >> 16);
}

__device__ __forceinline__ void gl_lds16(const void* g, void* l){
  __builtin_amdgcn_global_load_lds((const __attribute__((address_space(1))) char*)g,
                                   (__attribute__((address_space(3))) char*)l, 16, 0, 0);
}

// ---------------- router: logits fp32 (exact), softmax, top-2, scatter; emits bf16 x ---------
__global__ void router_k(const float* __restrict__ x, const float* __restrict__ Wg,
                         const float* __restrict__ bg, float* __restrict__ logits,
                         int* __restrict__ cnt, int* __restrict__ elist, float* __restrict__ wslot,
                         ushort_t* __restrict__ Xbf){
  int t = blockIdx.x;
  int l = threadIdx.x;
  const float4* xr = (const float4*)(x + (size_t)t * DMODEL);
  ushort_t* xb = Xbf + (size_t)t * DMODEL;
  float acc[NEXP];
  #pragma unroll
  for (int e=0;e<NEXP;e++) acc[e]=0.f;
  #pragma unroll
  for (int it=0; it<4; ++it){
    int i4 = it*64 + l;
    float4 v = xr[i4];
    const float* w0 = Wg + (size_t)(4*i4)*NEXP;
    #pragma unroll
    for (int e=0;e<NEXP;e++)
      acc[e] += v.x*w0[e] + v.y*w0[NEXP+e] + v.z*w0[2*NEXP+e] + v.w*w0[3*NEXP+e];
    ushort4 o; o.x=f2bf(v.x); o.y=f2bf(v.y); o.z=f2bf(v.z); o.w=f2bf(v.w);
    *(ushort4*)(xb + 4*i4) = o;
  }
  #pragma unroll
  for (int e=0;e<NEXP;e++){
    float v = acc[e];
    #pragma unroll
    for (int s=32;s>0;s>>=1) v += __shfl_xor(v,s);
    acc[e]=v;
  }
  if (l==0){
    float lg[NEXP]; float m=-1e30f;
    #pragma unroll
    for (int e=0;e<NEXP;e++){ lg[e]=acc[e]+bg[e]; m = fmaxf(m,lg[e]); }
    float p[NEXP];
    #pragma unroll
    for (int e=0;e<NEXP;e++) p[e]=__expf(lg[e]-m);
    int e0=0;
    #pragma unroll
    for (int e=1;e<NEXP;e++) if (p[e]>p[e0]) e0=e;      // strict > : lower idx wins ties
    int e1=(e0==0)?1:0;
    #pragma unroll
    for (int e=0;e<NEXP;e++) if (e!=e0 && p[e]>p[e1]) e1=e;
    float ps=p[e0]+p[e1];
    float w0=p[e0]/ps, w1=p[e1]/ps;
    #pragma unroll
    for (int e=0;e<NEXP;e++) logits[(size_t)t*NEXP+e]=lg[e];
    wslot[t*2+0]=w0; wslot[t*2+1]=w1;
    int p0=atomicAdd(&cnt[e0],1); elist[e0*N_TOK+p0]=t*2+0;
    int p1=atomicAdd(&cnt[e1],1); elist[e1*N_TOK+p1]=t*2+1;
  }
}

__global__ void scan_k(const int* __restrict__ cnt, int* __restrict__ offs){
  if (threadIdx.x==0 && blockIdx.x==0){
    int s=0;
    for (int e=0;e<NEXP;e++){ offs[e]=s; s+=cnt[e]; }
    offs[NEXP]=s;
  }
}

// ---------------- gather bf16 rows into compacted Xg (one block per expanded row) ------------
__global__ void gather_k(const ushort_t* __restrict__ Xbf, const int* __restrict__ offs,
                         const int* __restrict__ elist, const float* __restrict__ wslot,
                         ushort_t* __restrict__ Xg, int* __restrict__ rowslot, float* __restrict__ roww){
  int r = blockIdx.x;
  int e = 0;
  #pragma unroll
  for (int k=1;k<NEXP;k++) if (r >= offs[k]) e = k;
  int i = r - offs[e];
  int entry = elist[e*N_TOK+i];
  int t = entry>>1;
  int tid = threadIdx.x;
  ushort4 v = *(const ushort4*)(Xbf + (size_t)t*DMODEL + tid*4);
  *(ushort4*)(Xg + (size_t)r*DMODEL + tid*4) = v;
  if (tid==0){ rowslot[r]=entry; roww[r]=wslot[entry]; }
}

// ---------------- weight transpose + fp32->bf16: [k][f] -> [f][k], vectorized ----------------
__global__ void transpose_k(const float* __restrict__ Ww, const float* __restrict__ Wv,
                            const float* __restrict__ Wo,
                            ushort_t* __restrict__ WwT, ushort_t* __restrict__ WvT,
                            ushort_t* __restrict__ WoT){
  __shared__ ushort_t tile[64][68];
  int z = blockIdx.z;
  const float* src; ushort_t* dst; int K, F;
  if (z < 8)      { src = Ww + (size_t)z*DMODEL*DFFC;      dst = WwT + (size_t)z*DFFC*DMODEL;      K=DMODEL; F=DFFC; }
  else if (z < 16){ src = Wv + (size_t)(z-8)*DMODEL*DFFC;  dst = WvT + (size_t)(z-8)*DFFC*DMODEL;  K=DMODEL; F=DFFC; }
  else            { src = Wo + (size_t)(z-16)*DFFC*DMODEL; dst = WoT + (size_t)(z-16)*DMODEL*DFFC; K=DFFC; F=DMODEL; }
  int f0 = blockIdx.x*64, k0 = blockIdx.y*64;
  if (f0 >= F || k0 >= K) return;
  int tid = threadIdx.x;
  #pragma unroll
  for (int it=0; it<4; ++it){
    int idx = it*256 + tid;
    int r = idx>>4, c4 = idx&15;
    float4 v = *(const float4*)&src[(size_t)(k0+r)*F + f0 + c4*4];
    ushort4 o; o.x=f2bf(v.x); o.y=f2bf(v.y); o.z=f2bf(v.z); o.w=f2bf(v.w);
    *(ushort4*)&tile[r][c4*4] = o;
  }
  __syncthreads();
  #pragma unroll
  for (int it=0; it<4; ++it){
    int idx = it*256 + tid;
    int c = idx>>4;
    int j = idx&15;
    ushort4 o;
    o.x = tile[4*j+0][c]; o.y = tile[4*j+1][c]; o.z = tile[4*j+2][c]; o.w = tile[4*j+3][c];
    *(ushort4*)&dst[(size_t)(f0+c)*K + k0 + 4*j] = o;
  }
}

// swizzled fragment element-offset inside a [rows][64] bf16 tile (128B rows, 8 slots of 16B)
__device__ __forceinline__ int frag_off(int row, int slotc){
  return row*64 + ((slotc ^ (row & 7)))*8;
}

// ---------------- GEMM1: H = silu(Xg@Ww+bw)*(Xg@Wv+bv); BM=256,BN=128,BK=64, dual-B ---------
// 8 waves (2M x 4N). Counted-vmcnt pipelined dbuf. LDS = 64+32+32 = 128 KB.
__global__ __launch_bounds__(512,2) void gemm1_k(const ushort_t* __restrict__ Xg,
    const ushort_t* __restrict__ WwT, const ushort_t* __restrict__ WvT,
    const float* __restrict__ bw, const float* __restrict__ bv,
    const int* __restrict__ cnt, const int* __restrict__ offs,
    ushort_t* __restrict__ H){
  __shared__ ushort_t As[2][256*64];
  __shared__ ushort_t Bws[2][128*64];
  __shared__ ushort_t Bvs[2][128*64];
  int e  = blockIdx.y >> 5;
  int mt = blockIdx.y & 31;
  int cnte = cnt[e];
  if (mt*256 >= cnte) return;
  int row0 = offs[e] + mt*256;
  int f0 = blockIdx.x * 128;
  const ushort_t* A0  = Xg  + (size_t)row0*DMODEL;
  const ushort_t* B0w = WwT + (size_t)e*DFFC*DMODEL + (size_t)f0*DMODEL;
  const ushort_t* B0v = WvT + (size_t)e*DFFC*DMODEL + (size_t)f0*DMODEL;
  int tid = threadIdx.x;
  int w = tid>>6, l = tid&63;
  int wr = w>>2, wc = w&3;          // wave: rows [wr*128,+128), f-cols [wc*32,+32)

  // ---- precomputed stage addressing (per-thread) ----
  int sw = ((l&7) ^ (l>>3))*8;      // inverse-swizzled k-slot (element units)
  size_t aSrc[4]; int aDst[4];
  #pragma unroll
  for (int j=0;j<4;j++){
    int c = w*4+j;  int row = c*8 + (l>>3);
    aSrc[j] = (size_t)row*DMODEL + sw;  aDst[j] = c*512;
  }
  const ushort_t* Bsrc0 = (w<4) ? B0w : B0v;
  size_t bSrc[4]; int bDst[4];
  #pragma unroll
  for (int j=0;j<4;j++){
    int c = (w&3)*4+j;  int row = c*8 + (l>>3);
    bSrc[j] = (size_t)row*DMODEL + sw;  bDst[j] = c*512;
  }
  // ---- precomputed fragment offsets ----
  int aOff[8][2], bOff[2][2];
  #pragma unroll
  for (int m=0;m<8;m++)
    #pragma unroll
    for (int ks=0;ks<2;ks++)
      aOff[m][ks] = frag_off(wr*128 + m*16 + (l&15), ks*4 + (l>>4));
  #pragma unroll
  for (int n=0;n<2;n++)
    #pragma unroll
    for (int ks=0;ks<2;ks++)
      bOff[n][ks] = frag_off(wc*32 + n*16 + (l&15), ks*4 + (l>>4));

  float4v accw[8][2], accv[8][2];
  #pragma unroll
  for (int m=0;m<8;m++)
    #pragma unroll
    for (int n=0;n<2;n++){ accw[m][n]=(float4v){0,0,0,0}; accv[m][n]=(float4v){0,0,0,0}; }

  // prologue: stage tile 0 into buf 0
  #pragma unroll
  for (int j=0;j<4;j++) gl_lds16(A0 + aSrc[j], &As[0][aDst[j]]);
  ushort_t* bB0 = (w<4) ? Bws[0] : Bvs[0];
  #pragma unroll
  for (int j=0;j<4;j++) gl_lds16(Bsrc0 + bSrc[j], &bB0[bDst[j]]);

  const int KT = DMODEL/64;   // 16
  for (int t=0; t<KT; ++t){
    int p = t & 1;
    if (t+1 < KT){
      size_t k0 = (size_t)(t+1)*64;
      #pragma unroll
      for (int j=0;j<4;j++) gl_lds16(A0 + k0 + aSrc[j], &As[p^1][aDst[j]]);
      ushort_t* bB = (w<4) ? Bws[p^1] : Bvs[p^1];
      #pragma unroll
      for (int j=0;j<4;j++) gl_lds16(Bsrc0 + k0 + bSrc[j], &bB[bDst[j]]);
      asm volatile("s_waitcnt vmcnt(8)" ::: "memory");   // tile t resident; t+1 in flight
    } else {
      asm volatile("s_waitcnt vmcnt(0)" ::: "memory");
    }
    __builtin_amdgcn_s_barrier();
    __builtin_amdgcn_sched_barrier(0);
    const ushort_t* Ab  = As[p];
    const ushort_t* Bwb = Bws[p];
    const ushort_t* Bvb = Bvs[p];
    short8v bfw[2][2], bfv[2][2];
    #pragma unroll
    for (int n=0;n<2;n++)
      #pragma unroll
      for (int ks=0;ks<2;ks++){
        bfw[n][ks] = *(const short8v*)&Bwb[bOff[n][ks]];
        bfv[n][ks] = *(const short8v*)&Bvb[bOff[n][ks]];
      }
    #pragma unroll
    for (int q=0;q<4;q++){
      short8v a_[2][2];
      #pragma unroll
      for (int mi=0;mi<2;mi++)
        #pragma unroll
        for (int ks=0;ks<2;ks++)
          a_[mi][ks] = *(const short8v*)&Ab[aOff[q*2+mi][ks]];
      __builtin_amdgcn_s_setprio(1);
      #pragma unroll
      for (int mi=0;mi<2;mi++)
        #pragma unroll
        for (int n=0;n<2;n++)
          #pragma unroll
          for (int ks=0;ks<2;ks++){
            accw[q*2+mi][n] = __builtin_amdgcn_mfma_f32_16x16x32_bf16(a_[mi][ks], bfw[n][ks], accw[q*2+mi][n], 0,0,0);
            accv[q*2+mi][n] = __builtin_amdgcn_mfma_f32_16x16x32_bf16(a_[mi][ks], bfv[n][ks], accv[q*2+mi][n], 0,0,0);
          }
      __builtin_amdgcn_s_setprio(0);
    }
    __builtin_amdgcn_sched_barrier(0);
    __builtin_amdgcn_s_barrier();       // buf[p] free for overwrite next iter
    __builtin_amdgcn_sched_barrier(0);
  }

  int rows_valid = cnte - mt*256; if (rows_valid>256) rows_valid=256;
  #pragma unroll
  for (int m=0;m<8;m++){
    #pragma unroll
    for (int r=0;r<4;r++){
      int row_local = wr*128 + m*16 + (l>>4)*4 + r;
      if (row_local < rows_valid){
        size_t hbase = (size_t)(row0 + row_local)*DFFC;
        #pragma unroll
        for (int n=0;n<2;n++){
          int f = f0 + wc*32 + n*16 + (l&15);
          float wx = accw[m][n][r] + bw[e*DFFC + f];
          float vx = accv[m][n][r] + bv[e*DFFC + f];
          float h = (wx / (1.f + __expf(-wx))) * vx;
          H[hbase + f] = f2bf(h);
        }
      }
    }
  }
}

// ---------------- GEMM2: out[t] += w*(H@Wo + bo); BM=256,BN=128,BK=64 ----------------
__global__ __launch_bounds__(512,2) void gemm2_k(const ushort_t* __restrict__ H,
    const ushort_t* __restrict__ WoT, const float* __restrict__ bo,
    const int* __restrict__ cnt, const int* __restrict__ offs,
    const int* __restrict__ rowslot, const float* __restrict__ roww,
    float* __restrict__ out){
  __shared__ ushort_t As[2][256*64];
  __shared__ ushort_t Bs[2][128*64];      // 96 KB
  int e  = blockIdx.y >> 5;
  int mt = blockIdx.y & 31;
  int cnte = cnt[e];
  if (mt*256 >= cnte) return;
  int row0 = offs[e] + mt*256;
  int d0 = blockIdx.x * 128;
  const ushort_t* A0 = H   + (size_t)row0*DFFC;
  const ushort_t* B0 = WoT + (size_t)e*DMODEL*DFFC + (size_t)d0*DFFC;
  int tid = threadIdx.x;
  int w = tid>>6, l = tid&63;
  int wr = w>>2, wc = w&3;          // wave: rows [wr*128,+128), d-cols [wc*32,+32)

  int sw = ((l&7) ^ (l>>3))*8;
  size_t aSrc[4]; int aDst[4];
  #pragma unroll
  for (int j=0;j<4;j++){
    int c = w*4+j;  int row = c*8 + (l>>3);
    aSrc[j] = (size_t)row*DFFC + sw;  aDst[j] = c*512;
  }
  size_t bSrc[2]; int bDst[2];
  #pragma unroll
  for (int j=0;j<2;j++){
    int c = w*2+j;  int row = c*8 + (l>>3);
    bSrc[j] = (size_t)row*DFFC + sw;  bDst[j] = c*512;
  }
  int aOff[8][2], bOff[2][2];
  #pragma unroll
  for (int m=0;m<8;m++)
    #pragma unroll
    for (int ks=0;ks<2;ks++)
      aOff[m][ks] = frag_off(wr*128 + m*16 + (l&15), ks*4 + (l>>4));
  #pragma unroll
  for (int n=0;n<2;n++)
    #pragma unroll
    for (int ks=0;ks<2;ks++)
      bOff[n][ks] = frag_off(wc*32 + n*16 + (l&15), ks*4 + (l>>4));

  float4v acc[8][2];
  #pragma unroll
  for (int m=0;m<8;m++)
    #pragma unroll
    for (int n=0;n<2;n++) acc[m][n]=(float4v){0,0,0,0};

  #pragma unroll
  for (int j=0;j<4;j++) gl_lds16(A0 + aSrc[j], &As[0][aDst[j]]);
  #pragma unroll
  for (int j=0;j<2;j++) gl_lds16(B0 + bSrc[j], &Bs[0][bDst[j]]);

  const int KT = DFFC/64;     // 32
  for (int t=0; t<KT; ++t){
    int p = t & 1;
    if (t+1 < KT){
      size_t k0 = (size_t)(t+1)*64;
      #pragma unroll
      for (int j=0;j<4;j++) gl_lds16(A0 + k0 + aSrc[j], &As[p^1][aDst[j]]);
      #pragma unroll
      for (int j=0;j<2;j++) gl_lds16(B0 + k0 + bSrc[j], &Bs[p^1][bDst[j]]);
      asm volatile("s_waitcnt vmcnt(6)" ::: "memory");
    } else {
      asm volatile("s_waitcnt vmcnt(0)" ::: "memory");
    }
    __builtin_amdgcn_s_barrier();
    __builtin_amdgcn_sched_barrier(0);
    const ushort_t* Ab = As[p];
    const ushort_t* Bb = Bs[p];
    short8v bf[2][2];
    #pragma unroll
    for (int n=0;n<2;n++)
      #pragma unroll
      for (int ks=0;ks<2;ks++)
        bf[n][ks] = *(const short8v*)&Bb[bOff[n][ks]];
    #pragma unroll
    for (int q=0;q<4;q++){
      short8v a_[2][2];
      #pragma unroll
      for (int mi=0;mi<2;mi++)
        #pragma unroll
        for (int ks=0;ks<2;ks++)
          a_[mi][ks] = *(const short8v*)&Ab[aOff[q*2+mi][ks]];
      __builtin_amdgcn_s_setprio(1);
      #pragma unroll
      for (int mi=0;mi<2;mi++)
        #pragma unroll
        for (int n=0;n<2;n++)
          #pragma unroll
          for (int ks=0;ks<2;ks++)
            acc[q*2+mi][n] = __builtin_amdgcn_mfma_f32_16x16x32_bf16(a_[mi][ks], bf[n][ks], acc[q*2+mi][n], 0,0,0);
      __builtin_amdgcn_s_setprio(0);
    }
    __builtin_amdgcn_sched_barrier(0);
    __builtin_amdgcn_s_barrier();
    __builtin_amdgcn_sched_barrier(0);
  }

  int rows_valid = cnte - mt*256; if (rows_valid>256) rows_valid=256;
  #pragma unroll
  for (int m=0;m<8;m++){
    #pragma unroll
    for (int r=0;r<4;r++){
      int row_local = wr*128 + m*16 + (l>>4)*4 + r;
      if (row_local < rows_valid){
        int gr = row0 + row_local;
        int entry = rowslot[gr];
        int tk = entry>>1;
        float wgt = roww[gr];
        float* obase = out + (size_t)tk*DMODEL;
        #pragma unroll
        for (int n=0;n<2;n++){
          int d = d0 + wc*32 + n*16 + (l&15);
          atomicAdd(&obase[d], wgt * (acc[m][n][r] + bo[e*DMODEL + d]));
        }
      }
    }
  }
}

extern "C" void kernel_launch(void* const* d_in, const int* in_sizes, int n_in,
                              void* d_out, int out_size, void* d_ws, size_t ws_size,
                              hipStream_t stream){
  const float* x   = (const float*)d_in[0];
  const float* Wg  = (const float*)d_in[1];
  const float* bg  = (const float*)d_in[2];
  const float* Ww  = (const float*)d_in[3];
  const float* bwp = (const float*)d_in[4];
  const float* Wv  = (const float*)d_in[5];
  const float* bvp = (const float*)d_in[6];
  const float* Wo  = (const float*)d_in[7];
  const float* bop = (const float*)d_in[8];
  float* out = (float*)d_out;
  float* logits = out + (size_t)N_TOK*DMODEL;

  char* cur = (char*)d_ws;
  auto alloc = [&](size_t b)->char*{ char* p=cur; cur += (b+255)&~(size_t)255; return p; };
  int*      cnt     = (int*)     alloc(NEXP*4);
  int*      offs    = (int*)     alloc((NEXP+1)*4);
  float*    wslot   = (float*)   alloc((size_t)NR*4);
  int*      elist   = (int*)     alloc((size_t)NEXP*N_TOK*4);
  int*      rowslot = (int*)     alloc((size_t)NRP*4);
  float*    roww    = (float*)   alloc((size_t)NRP*4);
  ushort_t* Xbf     = (ushort_t*)alloc((size_t)N_TOK*DMODEL*2);
  ushort_t* Xg      = (ushort_t*)alloc((size_t)NRP*DMODEL*2);
  ushort_t* Hb      = (ushort_t*)alloc((size_t)NRP*DFFC*2);
  ushort_t* WwT     = (ushort_t*)alloc((size_t)NEXP*DFFC*DMODEL*2);
  ushort_t* WvT     = (ushort_t*)alloc((size_t)NEXP*DFFC*DMODEL*2);
  ushort_t* WoT     = (ushort_t*)alloc((size_t)NEXP*DMODEL*DFFC*2);
  (void)ws_size; (void)in_sizes; (void)n_in; (void)out_size;

  hipMemsetAsync(cnt, 0, NEXP*4, stream);
  hipMemsetAsync(out, 0, (size_t)N_TOK*DMODEL*4, stream);   // gemm2 accumulates atomically
  router_k<<<N_TOK, 64, 0, stream>>>(x, Wg, bg, logits, cnt, elist, wslot, Xbf);
  scan_k<<<1, 1, 0, stream>>>(cnt, offs);
  gather_k<<<NR, 256, 0, stream>>>(Xbf, offs, elist, wslot, Xg, rowslot, roww);
  transpose_k<<<dim3(32, 32, 24), 256, 0, stream>>>(Ww, Wv, Wo, WwT, WvT, WoT);
  gemm1_k<<<dim3(DFFC/128, NEXP*32), 512, 0, stream>>>(Xg, WwT, WvT, bwp, bvp, cnt, offs, Hb);
  gemm2_k<<<dim3(DMODEL/128, NEXP*32), 512, 0, stream>>>(Hb, WoT, bop, cnt, offs, rowslot, roww, out);
}